// Round 4
// baseline (199.354 us; speedup 1.0000x reference)
//
#include <hip/hip_runtime.h>
#include <hip/hip_bf16.h>
#include <stdint.h>

typedef __bf16 bf16x8 __attribute__((ext_vector_type(8)));
typedef __bf16 bf16x4 __attribute__((ext_vector_type(4)));
typedef float  f32x4  __attribute__((ext_vector_type(4)));
typedef unsigned int u32x4 __attribute__((ext_vector_type(4)));

#define D_MODEL 1024
#define NUM_HEADS 16
#define D_K 64
#define BATCH 2
#define SEQ 2048
#define M_TOTAL (BATCH * SEQ)   // 4096

// 0.125 (1/sqrt(64)) * log2(e): folded into Q at the qkv epilogue so the
// attention softmax is a bare exp2 (v_exp_f32), no per-element scale mul.
#define Q_SCALE 0.18033688011112042f

static __device__ __forceinline__ bf16x8 load8(const __bf16* p) {
    return *reinterpret_cast<const bf16x8*>(p);
}

#define MFMA16(a, b, c) __builtin_amdgcn_mfma_f32_16x16x32_bf16((a), (b), (c), 0, 0, 0)

// Async global->LDS, 16B per lane. LDS dest = wave-uniform base + lane*16.
static __device__ __forceinline__ void gload16(const void* g, const void* lds) {
    __builtin_amdgcn_global_load_lds(
        (const __attribute__((address_space(1))) uint32_t*)g,
        (__attribute__((address_space(3))) uint32_t*)lds,
        16, 0, 0);
}

// Pack two f32 -> one u32 of 2 bf16 (lo = first arg). No builtin on gfx950.
static __device__ __forceinline__ uint32_t cvtpk(float lo, float hi) {
    uint32_t r;
    asm("v_cvt_pk_bf16_f32 %0, %1, %2" : "=v"(r) : "v"(lo), "v"(hi));
    return r;
}
// CDNA4 zip semantics ("DST rows 2:3 <-> SRC rows 0:1", rows = 16 lanes):
//   swap32: a' = (a@q0, a@q1, b@q0, b@q1), b' = (a@q2, a@q3, b@q2, b@q3)
static __device__ __forceinline__ void swap32(uint32_t& a, uint32_t& b) {
    asm("v_permlane32_swap_b32 %0, %1" : "+v"(a), "+v"(b));
}
// swap16 ("DST odd rows <-> SRC even rows"):
//   a' = (a@q0, b@q0, a@q2, b@q2), b' = (a@q1, b@q1, a@q3, b@q3)
static __device__ __forceinline__ void swap16(uint32_t& a, uint32_t& b) {
    asm("v_permlane16_swap_b32 %0, %1" : "+v"(a), "+v"(b));
}

// ---------------------------------------------------------------------------
// One launch: x (2048 blocks) + 4 weight matrices (512 blocks each) fp32->bf16.
// ---------------------------------------------------------------------------
__global__ __launch_bounds__(256) void convert_all(
    const float* __restrict__ X,
    const float* __restrict__ Wq, const float* __restrict__ Wk,
    const float* __restrict__ Wv, const float* __restrict__ Wo,
    __bf16* __restrict__ xb,
    __bf16* __restrict__ dq, __bf16* __restrict__ dk,
    __bf16* __restrict__ dv, __bf16* __restrict__ dw)
{
    const float* src; __bf16* dst; size_t idx;
    if (blockIdx.x < 2048) {
        src = X; dst = xb;
        idx = (size_t)blockIdx.x * 256 + threadIdx.x;
    } else {
        const int wb  = blockIdx.x - 2048;
        const int sel = wb >> 9;
        src = (sel == 0) ? Wq : (sel == 1) ? Wk : (sel == 2) ? Wv : Wo;
        dst = (sel == 0) ? dq : (sel == 1) ? dk : (sel == 2) ? dv : dw;
        idx = (size_t)(wb & 511) * 256 + threadIdx.x;
    }
    const f32x4 a = *reinterpret_cast<const f32x4*>(src + idx * 8);
    const f32x4 b = *reinterpret_cast<const f32x4*>(src + idx * 8 + 4);
    bf16x8 r;
#pragma unroll
    for (int e = 0; e < 4; e++) { r[e] = (__bf16)a[e]; r[4 + e] = (__bf16)b[e]; }
    *reinterpret_cast<bf16x8*>(dst + idx * 8) = r;
}

// ---------------------------------------------------------------------------
// QKV GEMM: 128x128 tile, BK=64, swizzled gload16 staging. Q output is
// pre-scaled by Q_SCALE. V output transposed through LDS -> coalesced V^T.
// grid = (32, 24), block = 256.
// ---------------------------------------------------------------------------
__global__ __launch_bounds__(256) void qkv_kernel(
    const __bf16* __restrict__ Xb,
    const __bf16* __restrict__ Wqb,
    const __bf16* __restrict__ Wkb,
    const __bf16* __restrict__ Wvb,
    __bf16* __restrict__ Qb,
    __bf16* __restrict__ Kb,
    __bf16* __restrict__ Vtg)
{
    __shared__ alignas(16) char smem[34816];   // As(16K)+Bs(16K); V scratch 34K
    __bf16* As = (__bf16*)smem;                // [128][64], chunk-swizzled
    __bf16* Bs = As + 128 * 64;

    const int lane = threadIdx.x & 63;
    const int wid  = threadIdx.x >> 6;
    const int m    = lane & 15;
    const int quad = lane >> 4;
    const int wrow = wid >> 1, wcol = wid & 1;
    const int row0 = blockIdx.x * 128;
    const int col0 = blockIdx.y * 128;
    const int wsel = col0 >> 10;
    const int lcol0 = col0 & 1023;

    const __bf16* W = (wsel == 0) ? Wqb : (wsel == 1) ? Wkb : Wvb;

    f32x4 acc[4][4];
#pragma unroll
    for (int i = 0; i < 4; i++)
#pragma unroll
        for (int j = 0; j < 4; j++) acc[i][j] = (f32x4){0.f, 0.f, 0.f, 0.f};

    for (int k0 = 0; k0 < D_MODEL; k0 += 64) {
#pragma unroll
        for (int i = 0; i < 4; i++) {
            const int slot = wid * 256 + i * 64 + lane;
            const int row  = slot >> 3;
            const int cg   = (slot & 7) ^ (row & 7);
            gload16(Xb + (size_t)(row0 + row) * D_MODEL + k0 + cg * 8,
                    (const char*)As + (size_t)(wid * 256 + i * 64) * 16);
            gload16(W + (size_t)(lcol0 + row) * D_MODEL + k0 + cg * 8,
                    (const char*)Bs + (size_t)(wid * 256 + i * 64) * 16);
        }
        __syncthreads();

        bf16x8 a2[2][4], b2[2][4];
#pragma unroll
        for (int ks = 0; ks < 2; ks++) {
#pragma unroll
            for (int i = 0; i < 4; i++) {
                const int rA = wrow * 64 + i * 16 + m;
                a2[ks][i] = load8(As + rA * 64 + (((ks * 4 + quad) ^ (rA & 7)) * 8));
                const int rB = wcol * 64 + i * 16 + m;
                b2[ks][i] = load8(Bs + rB * 64 + (((ks * 4 + quad) ^ (rB & 7)) * 8));
            }
        }
#pragma unroll
        for (int ks = 0; ks < 2; ks++)
#pragma unroll
            for (int i = 0; i < 4; i++)
#pragma unroll
                for (int j = 0; j < 4; j++)
                    acc[i][j] = MFMA16(a2[ks][i], b2[ks][j], acc[i][j]);
        __syncthreads();
    }

    if (wsel < 2) {
        // Q (pre-scaled) / K: [bh][s][dk]
        __bf16* Out = wsel ? Kb : Qb;
        const float sc = wsel ? 1.f : Q_SCALE;
#pragma unroll
        for (int i = 0; i < 4; i++) {
#pragma unroll
            for (int r = 0; r < 4; r++) {
                const int R  = row0 + wrow * 64 + i * 16 + quad * 4 + r;
                const int bb = R >> 11;
                const int s  = R & (SEQ - 1);
#pragma unroll
                for (int j = 0; j < 4; j++) {
                    const int e  = lcol0 + wcol * 64 + j * 16 + m;
                    const int h  = e >> 6;
                    const int dk = e & (D_K - 1);
                    Out[((size_t)(bb * NUM_HEADS + h) * SEQ + s) * D_K + dk] =
                        (__bf16)(acc[i][j][r] * sc);
                }
            }
        }
    } else {
        // V: transpose tile through LDS, store coalesced V^T rows.
        __bf16* Ls = (__bf16*)smem;   // [128][136]
#pragma unroll
        for (int i = 0; i < 4; i++)
#pragma unroll
            for (int r = 0; r < 4; r++)
#pragma unroll
                for (int j = 0; j < 4; j++)
                    Ls[(wcol * 64 + j * 16 + m) * 136 +
                       wrow * 64 + i * 16 + quad * 4 + r] = (__bf16)acc[i][j][r];
        __syncthreads();
        const int bb   = row0 >> 11;
        const int sloc = row0 & (SEQ - 1);
#pragma unroll
        for (int i = 0; i < 8; i++) {
            const int c   = i * 256 + threadIdx.x;
            const int dkl = c >> 4;
            const int sc  = c & 15;
            const bf16x8 v = load8(Ls + dkl * 136 + sc * 8);
            const int e  = lcol0 + dkl;
            const int h  = e >> 6;
            const int dk = e & (D_K - 1);
            const int bh = bb * NUM_HEADS + h;
            *reinterpret_cast<bf16x8*>(
                Vtg + ((size_t)bh * D_K + dk) * SEQ + sloc + sc * 8) = v;
        }
    }
}

// ---------------------------------------------------------------------------
// Flash attention, causal. R14: QBLK = 128 q-rows per block (each wave owns
// TWO 16-row q-groups). K- and V-fragments are read from LDS ONCE per wave
// and feed both groups' MFMAs -> LDS bytes, staging bytes, and tile count
// per unit work all HALVE (the invariant R12/R13 didn't touch: per-CU tiles
// 66 -> ~34). grid = (32 bh, 16 strips), big strips first, 512 blocks.
// Double-buffered K/V staging, register-resident P (zip-permlane), ones-MFMA
// row sums. Near-diagonal masking per group: (k0+63 > qbase) predication,
// which degenerates to all-zero P for fully-masked groups (correct, ~1.5%
// wasted MFMA on the last tile of waves 0/1).
// ---------------------------------------------------------------------------
__global__ __launch_bounds__(256) void attn_kernel(
    const __bf16* __restrict__ Qb,
    const __bf16* __restrict__ Kb,
    const __bf16* __restrict__ Vtg,
    __bf16* __restrict__ Cc)
{
    __shared__ alignas(16) __bf16 Ks[2][64 * 64];  // ping-pong, 16 KB
    __shared__ alignas(16) __bf16 Vt[2][64 * 64];  // ping-pong, 16 KB

    const int lane = threadIdx.x & 63;
    const int wid  = threadIdx.x >> 6;
    const int m    = lane & 15;
    const int quad = lane >> 4;
    const int bh   = blockIdx.x;
    const int b    = bh >> 4;
    const int h    = bh & (NUM_HEADS - 1);
    const int sp   = 15 - blockIdx.y;              // 128-row strip, big first

    const __bf16* Qp = Qb  + (size_t)bh * SEQ * D_K;
    const __bf16* Kp = Kb  + (size_t)bh * SEQ * D_K;
    const __bf16* Vp = Vtg + (size_t)bh * D_K * SEQ;

    // staging lambda: 64x64 K tile + 64x64 V^T tile into buffer `buf`
    auto stage = [&](int k0, int buf) {
#pragma unroll
        for (int i = 0; i < 2; i++) {
            const int slot = wid * 128 + i * 64 + lane;
            const int row  = slot >> 3;
            const int cg   = (slot & 7) ^ (row & 7);
            gload16(Kp + (size_t)(k0 + row) * D_K + cg * 8,
                    (const char*)&Ks[buf][0] + (size_t)(wid * 128 + i * 64) * 16);
            gload16(Vp + (size_t)row * SEQ + k0 + cg * 8,
                    (const char*)&Vt[buf][0] + (size_t)(wid * 128 + i * 64) * 16);
        }
    };

    bf16x8 vone;
#pragma unroll
    for (int e = 0; e < 8; e++) vone[e] = (__bf16)1.0f;

    // wave's two q-groups: rows qb[g] .. qb[g]+15
    const int qb0 = sp * 128 + wid * 32;
    const int qb1 = qb0 + 16;

    const bf16x8 qA0 = load8(Qp + (size_t)(qb0 + m) * D_K + quad * 8);
    const bf16x8 qA1 = load8(Qp + (size_t)(qb0 + m) * D_K + 32 + quad * 8);
    const bf16x8 qC0 = load8(Qp + (size_t)(qb1 + m) * D_K + quad * 8);
    const bf16x8 qC1 = load8(Qp + (size_t)(qb1 + m) * D_K + 32 + quad * 8);

    f32x4 oacc[2][4];
#pragma unroll
    for (int g = 0; g < 2; g++)
#pragma unroll
        for (int c = 0; c < 4; c++) oacc[g][c] = (f32x4){0.f, 0.f, 0.f, 0.f};
    f32x4 accL[2];
    accL[0] = (f32x4){0.f, 0.f, 0.f, 0.f};
    accL[1] = (f32x4){0.f, 0.f, 0.f, 0.f};

    const int T = 2 * sp + 2;                      // tiles for this strip
    stage(0, 0);
    int cur = 0;
#pragma unroll 1
    for (int t = 0; t < T; t++) {
        __syncthreads();             // tile t's staging complete
        if (t + 1 < T) stage((t + 1) * 64, cur ^ 1);   // prefetch in flight
        const int  k0 = t * 64;
        const bool mk0 = (k0 + 63 > qb0);          // group 0 needs masking
        const bool mk1 = (k0 + 63 > qb1);          // group 1 needs masking
        const __bf16* Kc = &Ks[cur][0];
        const __bf16* Vc = &Vt[cur][0];

        // ---- S^T = K Q^T per group; exp2; pack to bf16 words.
        // Lane (m,quad) produces keys {kb*16+quad*4 .. +3} for q=qb[g]+m.
        uint32_t w0[2][4], w1[2][4];
#pragma unroll
        for (int kb = 0; kb < 4; kb++) {
            const int rK = kb * 16 + m;
            const bf16x8 kfA = load8(Kc + rK * 64 + ((quad ^ (rK & 7)) * 8));
            const bf16x8 kfB = load8(Kc + rK * 64 + (((quad + 4) ^ (rK & 7)) * 8));
            f32x4 st0 = (f32x4){0.f, 0.f, 0.f, 0.f};
            st0 = MFMA16(kfA, qA0, st0);
            st0 = MFMA16(kfB, qA1, st0);
            f32x4 st1 = (f32x4){0.f, 0.f, 0.f, 0.f};
            st1 = MFMA16(kfA, qC0, st1);
            st1 = MFMA16(kfB, qC1, st1);
            const int keyb = k0 + kb * 16 + quad * 4;
            float e0[4], e1[4];
#pragma unroll
            for (int r = 0; r < 4; r++) {
                float e = __builtin_amdgcn_exp2f(st0[r]);
                if (mk0) e = (keyb + r <= qb0 + m) ? e : 0.f;
                e0[r] = e;
                float f = __builtin_amdgcn_exp2f(st1[r]);
                if (mk1) f = (keyb + r <= qb1 + m) ? f : 0.f;
                e1[r] = f;
            }
            w0[0][kb] = cvtpk(e0[0], e0[1]);
            w1[0][kb] = cvtpk(e0[2], e0[3]);
            w0[1][kb] = cvtpk(e1[0], e1[1]);
            w1[1][kb] = cvtpk(e1[2], e1[3]);
        }

        // ---- redistribute to A-fragments per group (zip semantics):
        //   (X=w[lo], Y=w[hi]); swap32; swap16 => X=word j, Y=word j+2.
        bf16x8 pfA[2], pfB[2];
#pragma unroll
        for (int g = 0; g < 2; g++) {
            uint32_t pa0 = w0[g][0], pa2 = w0[g][1]; swap32(pa0, pa2); swap16(pa0, pa2);
            uint32_t pa1 = w1[g][0], pa3 = w1[g][1]; swap32(pa1, pa3); swap16(pa1, pa3);
            uint32_t pb0 = w0[g][2], pb2 = w0[g][3]; swap32(pb0, pb2); swap16(pb0, pb2);
            uint32_t pb1 = w1[g][2], pb3 = w1[g][3]; swap32(pb1, pb3); swap16(pb1, pb3);
            const u32x4 ua = (u32x4){pa0, pa1, pa2, pa3};
            const u32x4 ub = (u32x4){pb0, pb1, pb2, pb3};
            pfA[g] = __builtin_bit_cast(bf16x8, ua);
            pfB[g] = __builtin_bit_cast(bf16x8, ub);

            // row-sum via ones-MFMA: accL[g][r] = sum_k P[q=quad*4+r][k]
            accL[g] = MFMA16(pfA[g], vone, accL[g]);
            accL[g] = MFMA16(pfB[g], vone, accL[g]);
        }

        // ---- P.V : V fragments loaded ONCE, consumed by both groups ----
#pragma unroll
        for (int c = 0; c < 4; c++) {
            const int rV = c * 16 + m;
            const bf16x8 vfA = load8(Vc + rV * 64 + ((quad ^ (rV & 7)) * 8));
            const bf16x8 vfB = load8(Vc + rV * 64 + (((quad + 4) ^ (rV & 7)) * 8));
            oacc[0][c] = MFMA16(pfA[0], vfA, oacc[0][c]);
            oacc[0][c] = MFMA16(pfB[0], vfB, oacc[0][c]);
            oacc[1][c] = MFMA16(pfA[1], vfA, oacc[1][c]);
            oacc[1][c] = MFMA16(pfB[1], vfB, oacc[1][c]);
        }
        cur ^= 1;
    }

    // ---- epilogue: l is per-register in accL[g] ----
#pragma unroll
    for (int g = 0; g < 2; g++) {
        const int qb = g ? qb1 : qb0;
#pragma unroll
        for (int r = 0; r < 4; r++) {
            const float inv = 1.f / accL[g][r];
            const int srow = qb + quad * 4 + r;
#pragma unroll
            for (int c = 0; c < 4; c++) {
                const size_t o = ((size_t)(b * SEQ + srow)) * D_MODEL + h * D_K + c * 16 + m;
                Cc[o] = (__bf16)(oacc[g][c][r] * inv);
            }
        }
    }
}

// ---------------------------------------------------------------------------
// Output projection: Out = Cc * Wo^T + bo (fp32). 64x128 tile -> grid
// (64, 8) = 512 blocks = 2/CU.
// ---------------------------------------------------------------------------
__global__ __launch_bounds__(256) void oproj_kernel(
    const __bf16* __restrict__ Cc,
    const __bf16* __restrict__ Wob,
    const float* __restrict__ bo,
    float* __restrict__ Out)
{
    __shared__ alignas(16) __bf16 As[64 * 64];    // 8 KB
    __shared__ alignas(16) __bf16 Bs[128 * 64];   // 16 KB

    const int lane = threadIdx.x & 63;
    const int wid  = threadIdx.x >> 6;
    const int m    = lane & 15;
    const int quad = lane >> 4;
    const int wrow = wid >> 1, wcol = wid & 1;
    const int row0 = blockIdx.x * 64;
    const int col0 = blockIdx.y * 128;

    f32x4 acc[2][4];
#pragma unroll
    for (int i = 0; i < 2; i++)
#pragma unroll
        for (int j = 0; j < 4; j++) acc[i][j] = (f32x4){0.f, 0.f, 0.f, 0.f};

    for (int k0 = 0; k0 < D_MODEL; k0 += 64) {
#pragma unroll
        for (int i = 0; i < 2; i++) {
            const int slot = wid * 128 + i * 64 + lane;
            const int row  = slot >> 3;
            const int cg   = (slot & 7) ^ (row & 7);
            gload16(Cc + (size_t)(row0 + row) * D_MODEL + k0 + cg * 8,
                    (const char*)As + (size_t)(wid * 128 + i * 64) * 16);
        }
#pragma unroll
        for (int i = 0; i < 4; i++) {
            const int slot = wid * 256 + i * 64 + lane;
            const int row  = slot >> 3;
            const int cg   = (slot & 7) ^ (row & 7);
            gload16(Wob + (size_t)(col0 + row) * D_MODEL + k0 + cg * 8,
                    (const char*)Bs + (size_t)(wid * 256 + i * 64) * 16);
        }
        __syncthreads();

        bf16x8 a2[2][2], b2[2][4];
#pragma unroll
        for (int ks = 0; ks < 2; ks++) {
#pragma unroll
            for (int i = 0; i < 2; i++) {
                const int rA = wrow * 32 + i * 16 + m;
                a2[ks][i] = load8(As + rA * 64 + (((ks * 4 + quad) ^ (rA & 7)) * 8));
            }
#pragma unroll
            for (int j = 0; j < 4; j++) {
                const int rB = wcol * 64 + j * 16 + m;
                b2[ks][j] = load8(Bs + rB * 64 + (((ks * 4 + quad) ^ (rB & 7)) * 8));
            }
        }
#pragma unroll
        for (int ks = 0; ks < 2; ks++)
#pragma unroll
            for (int i = 0; i < 2; i++)
#pragma unroll
                for (int j = 0; j < 4; j++)
                    acc[i][j] = MFMA16(a2[ks][i], b2[ks][j], acc[i][j]);
        __syncthreads();
    }

#pragma unroll
    for (int i = 0; i < 2; i++) {
#pragma unroll
        for (int r = 0; r < 4; r++) {
            const int R = row0 + wrow * 32 + i * 16 + quad * 4 + r;
#pragma unroll
            for (int j = 0; j < 4; j++) {
                const int E = col0 + wcol * 64 + j * 16 + m;
                Out[(size_t)R * D_MODEL + E] = acc[i][j][r] + bo[E];
            }
        }
    }
}

// ---------------------------------------------------------------------------
extern "C" void kernel_launch(void* const* d_in, const int* in_sizes, int n_in,
                              void* d_out, int out_size, void* d_ws, size_t ws_size,
                              hipStream_t stream) {
    const float* x  = (const float*)d_in[0];
    const float* Wq = (const float*)d_in[1];
    const float* Wk = (const float*)d_in[2];
    const float* Wv = (const float*)d_in[3];
    const float* Wo = (const float*)d_in[4];
    const float* bo = (const float*)d_in[5];
    // d_in[6] = causal mask — recomputed from indices, not read.

    const size_t elems  = (size_t)M_TOTAL * D_MODEL;   // 4194304
    const size_t welems = (size_t)D_MODEL * D_MODEL;   // 1048576
    __bf16* xb  = (__bf16*)d_ws;       // seg0: x (bf16) -> later Cc (aliased)
    __bf16* Qb  = xb + elems;
    __bf16* Kb  = Qb + elems;
    __bf16* Vtg = Kb + elems;          // [32][64][2048]  (V^T)
    __bf16* Wqb = Vtg + elems;
    __bf16* Wkb = Wqb + welems;
    __bf16* Wvb = Wkb + welems;
    __bf16* Wob = Wvb + welems;        // end: 40 MB
    __bf16* Cc  = xb;

    // 0) all fp32 -> bf16 conversions in one launch
    convert_all<<<dim3(4096), 256, 0, stream>>>(
        x, Wq, Wk, Wv, Wo, xb, Wqb, Wkb, Wvb, Wob);

    // 1) QKV projections (Q pre-scaled by 0.125*log2e)
    qkv_kernel<<<dim3(M_TOTAL / 128, 3 * D_MODEL / 128), 256, 0, stream>>>(
        xb, Wqb, Wkb, Wvb, Qb, Kb, Vtg);

    // 2) causal flash attention: QBLK=128 (two q-groups/wave), big-first
    attn_kernel<<<dim3(BATCH * NUM_HEADS, 16), 256, 0, stream>>>(
        Qb, Kb, Vtg, Cc);

    // 3) output projection + bias -> fp32 out
    oproj_kernel<<<dim3(M_TOTAL / 64, D_MODEL / 128), 256, 0, stream>>>(
        Cc, Wob, bo, (float*)d_out);
}

// Round 5
// 187.974 us; speedup vs baseline: 1.0605x; 1.0605x over previous
//
#include <hip/hip_runtime.h>
#include <hip/hip_bf16.h>
#include <stdint.h>

typedef __bf16 bf16x8 __attribute__((ext_vector_type(8)));
typedef __bf16 bf16x4 __attribute__((ext_vector_type(4)));
typedef float  f32x4  __attribute__((ext_vector_type(4)));
typedef unsigned int u32x4 __attribute__((ext_vector_type(4)));

#define D_MODEL 1024
#define NUM_HEADS 16
#define D_K 64
#define BATCH 2
#define SEQ 2048
#define M_TOTAL (BATCH * SEQ)   // 4096

// 0.125 (1/sqrt(64)) * log2(e): folded into Q at the qkv epilogue so the
// attention softmax is a bare exp2 (v_exp_f32), no per-element scale mul.
#define Q_SCALE 0.18033688011112042f

static __device__ __forceinline__ bf16x8 load8(const __bf16* p) {
    return *reinterpret_cast<const bf16x8*>(p);
}

#define MFMA16(a, b, c) __builtin_amdgcn_mfma_f32_16x16x32_bf16((a), (b), (c), 0, 0, 0)

// Async global->LDS, 16B per lane. LDS dest = wave-uniform base + lane*16.
static __device__ __forceinline__ void gload16(const void* g, const void* lds) {
    __builtin_amdgcn_global_load_lds(
        (const __attribute__((address_space(1))) uint32_t*)g,
        (__attribute__((address_space(3))) uint32_t*)lds,
        16, 0, 0);
}

// Pack two f32 -> one u32 of 2 bf16 (lo = first arg). No builtin on gfx950.
static __device__ __forceinline__ uint32_t cvtpk(float lo, float hi) {
    uint32_t r;
    asm("v_cvt_pk_bf16_f32 %0, %1, %2" : "=v"(r) : "v"(lo), "v"(hi));
    return r;
}
// CDNA4 zip semantics ("DST rows 2:3 <-> SRC rows 0:1", rows = 16 lanes):
//   swap32: a' = (a@q0, a@q1, b@q0, b@q1), b' = (a@q2, a@q3, b@q2, b@q3)
static __device__ __forceinline__ void swap32(uint32_t& a, uint32_t& b) {
    asm("v_permlane32_swap_b32 %0, %1" : "+v"(a), "+v"(b));
}
// swap16 ("DST odd rows <-> SRC even rows"):
//   a' = (a@q0, b@q0, a@q2, b@q2), b' = (a@q1, b@q1, a@q3, b@q3)
static __device__ __forceinline__ void swap16(uint32_t& a, uint32_t& b) {
    asm("v_permlane16_swap_b32 %0, %1" : "+v"(a), "+v"(b));
}

// ---------------------------------------------------------------------------
// One launch: x (2048 blocks) + 4 weight matrices (512 blocks each) fp32->bf16.
// ---------------------------------------------------------------------------
__global__ __launch_bounds__(256) void convert_all(
    const float* __restrict__ X,
    const float* __restrict__ Wq, const float* __restrict__ Wk,
    const float* __restrict__ Wv, const float* __restrict__ Wo,
    __bf16* __restrict__ xb,
    __bf16* __restrict__ dq, __bf16* __restrict__ dk,
    __bf16* __restrict__ dv, __bf16* __restrict__ dw)
{
    const float* src; __bf16* dst; size_t idx;
    if (blockIdx.x < 2048) {
        src = X; dst = xb;
        idx = (size_t)blockIdx.x * 256 + threadIdx.x;
    } else {
        const int wb  = blockIdx.x - 2048;
        const int sel = wb >> 9;
        src = (sel == 0) ? Wq : (sel == 1) ? Wk : (sel == 2) ? Wv : Wo;
        dst = (sel == 0) ? dq : (sel == 1) ? dk : (sel == 2) ? dv : dw;
        idx = (size_t)(wb & 511) * 256 + threadIdx.x;
    }
    const f32x4 a = *reinterpret_cast<const f32x4*>(src + idx * 8);
    const f32x4 b = *reinterpret_cast<const f32x4*>(src + idx * 8 + 4);
    bf16x8 r;
#pragma unroll
    for (int e = 0; e < 4; e++) { r[e] = (__bf16)a[e]; r[4 + e] = (__bf16)b[e]; }
    *reinterpret_cast<bf16x8*>(dst + idx * 8) = r;
}

// ---------------------------------------------------------------------------
// QKV GEMM: 128x128 tile, BK=64, swizzled gload16 staging. Q output is
// pre-scaled by Q_SCALE. V output transposed through LDS -> coalesced V^T.
// grid = (32, 24), block = 256.
// ---------------------------------------------------------------------------
__global__ __launch_bounds__(256) void qkv_kernel(
    const __bf16* __restrict__ Xb,
    const __bf16* __restrict__ Wqb,
    const __bf16* __restrict__ Wkb,
    const __bf16* __restrict__ Wvb,
    __bf16* __restrict__ Qb,
    __bf16* __restrict__ Kb,
    __bf16* __restrict__ Vtg)
{
    __shared__ alignas(16) char smem[34816];   // As(16K)+Bs(16K); V scratch 34K
    __bf16* As = (__bf16*)smem;                // [128][64], chunk-swizzled
    __bf16* Bs = As + 128 * 64;

    const int lane = threadIdx.x & 63;
    const int wid  = threadIdx.x >> 6;
    const int m    = lane & 15;
    const int quad = lane >> 4;
    const int wrow = wid >> 1, wcol = wid & 1;
    const int row0 = blockIdx.x * 128;
    const int col0 = blockIdx.y * 128;
    const int wsel = col0 >> 10;
    const int lcol0 = col0 & 1023;

    const __bf16* W = (wsel == 0) ? Wqb : (wsel == 1) ? Wkb : Wvb;

    f32x4 acc[4][4];
#pragma unroll
    for (int i = 0; i < 4; i++)
#pragma unroll
        for (int j = 0; j < 4; j++) acc[i][j] = (f32x4){0.f, 0.f, 0.f, 0.f};

    for (int k0 = 0; k0 < D_MODEL; k0 += 64) {
#pragma unroll
        for (int i = 0; i < 4; i++) {
            const int slot = wid * 256 + i * 64 + lane;
            const int row  = slot >> 3;
            const int cg   = (slot & 7) ^ (row & 7);
            gload16(Xb + (size_t)(row0 + row) * D_MODEL + k0 + cg * 8,
                    (const char*)As + (size_t)(wid * 256 + i * 64) * 16);
            gload16(W + (size_t)(lcol0 + row) * D_MODEL + k0 + cg * 8,
                    (const char*)Bs + (size_t)(wid * 256 + i * 64) * 16);
        }
        __syncthreads();

        bf16x8 a2[2][4], b2[2][4];
#pragma unroll
        for (int ks = 0; ks < 2; ks++) {
#pragma unroll
            for (int i = 0; i < 4; i++) {
                const int rA = wrow * 64 + i * 16 + m;
                a2[ks][i] = load8(As + rA * 64 + (((ks * 4 + quad) ^ (rA & 7)) * 8));
                const int rB = wcol * 64 + i * 16 + m;
                b2[ks][i] = load8(Bs + rB * 64 + (((ks * 4 + quad) ^ (rB & 7)) * 8));
            }
        }
#pragma unroll
        for (int ks = 0; ks < 2; ks++)
#pragma unroll
            for (int i = 0; i < 4; i++)
#pragma unroll
                for (int j = 0; j < 4; j++)
                    acc[i][j] = MFMA16(a2[ks][i], b2[ks][j], acc[i][j]);
        __syncthreads();
    }

    if (wsel < 2) {
        // Q (pre-scaled) / K: [bh][s][dk]
        __bf16* Out = wsel ? Kb : Qb;
        const float sc = wsel ? 1.f : Q_SCALE;
#pragma unroll
        for (int i = 0; i < 4; i++) {
#pragma unroll
            for (int r = 0; r < 4; r++) {
                const int R  = row0 + wrow * 64 + i * 16 + quad * 4 + r;
                const int bb = R >> 11;
                const int s  = R & (SEQ - 1);
#pragma unroll
                for (int j = 0; j < 4; j++) {
                    const int e  = lcol0 + wcol * 64 + j * 16 + m;
                    const int h  = e >> 6;
                    const int dk = e & (D_K - 1);
                    Out[((size_t)(bb * NUM_HEADS + h) * SEQ + s) * D_K + dk] =
                        (__bf16)(acc[i][j][r] * sc);
                }
            }
        }
    } else {
        // V: transpose tile through LDS, store coalesced V^T rows.
        __bf16* Ls = (__bf16*)smem;   // [128][136]
#pragma unroll
        for (int i = 0; i < 4; i++)
#pragma unroll
            for (int r = 0; r < 4; r++)
#pragma unroll
                for (int j = 0; j < 4; j++)
                    Ls[(wcol * 64 + j * 16 + m) * 136 +
                       wrow * 64 + i * 16 + quad * 4 + r] = (__bf16)acc[i][j][r];
        __syncthreads();
        const int bb   = row0 >> 11;
        const int sloc = row0 & (SEQ - 1);
#pragma unroll
        for (int i = 0; i < 8; i++) {
            const int c   = i * 256 + threadIdx.x;
            const int dkl = c >> 4;
            const int sc  = c & 15;
            const bf16x8 v = load8(Ls + dkl * 136 + sc * 8);
            const int e  = lcol0 + dkl;
            const int h  = e >> 6;
            const int dk = e & (D_K - 1);
            const int bh = bb * NUM_HEADS + h;
            *reinterpret_cast<bf16x8*>(
                Vtg + ((size_t)bh * D_K + dk) * SEQ + sloc + sc * 8) = v;
        }
    }
}

// ---------------------------------------------------------------------------
// Flash attention, causal, ONE STRIP PER BLOCK + DOUBLE-BUFFERED LDS staging.
// R15: reverted to the R13 configuration (QBLK=64, grid (32 bh, 32 strips),
// 1024 blocks = 4/CU, big strips first) -- the best verified point. R14's
// QBLK=128 halved traffic but doubled the per-tile latency chain and halved
// block-level parallelism -> regression (51.2 vs <=44.7 us).
// Register-resident P (zip-permlane), ones-MFMA row sums.
// ---------------------------------------------------------------------------
__global__ __launch_bounds__(256) void attn_kernel(
    const __bf16* __restrict__ Qb,
    const __bf16* __restrict__ Kb,
    const __bf16* __restrict__ Vtg,
    __bf16* __restrict__ Cc)
{
    __shared__ alignas(16) __bf16 Ks[2][64 * 64];  // ping-pong, 16 KB
    __shared__ alignas(16) __bf16 Vt[2][64 * 64];  // ping-pong, 16 KB

    const int lane = threadIdx.x & 63;
    const int wid  = threadIdx.x >> 6;
    const int m    = lane & 15;
    const int quad = lane >> 4;
    const int bh   = blockIdx.x;
    const int b    = bh >> 4;
    const int h    = bh & (NUM_HEADS - 1);
    const int s    = 31 - blockIdx.y;              // strip index, big first

    const __bf16* Qp = Qb  + (size_t)bh * SEQ * D_K;
    const __bf16* Kp = Kb  + (size_t)bh * SEQ * D_K;
    const __bf16* Vp = Vtg + (size_t)bh * D_K * SEQ;

    // staging lambda: 64x64 K tile + 64x64 V^T tile into buffer `buf`
    auto stage = [&](int k0, int buf) {
#pragma unroll
        for (int i = 0; i < 2; i++) {
            const int slot = wid * 128 + i * 64 + lane;
            const int row  = slot >> 3;
            const int cg   = (slot & 7) ^ (row & 7);
            gload16(Kp + (size_t)(k0 + row) * D_K + cg * 8,
                    (const char*)&Ks[buf][0] + (size_t)(wid * 128 + i * 64) * 16);
            gload16(Vp + (size_t)row * SEQ + k0 + cg * 8,
                    (const char*)&Vt[buf][0] + (size_t)(wid * 128 + i * 64) * 16);
        }
    };

    bf16x8 vone;
#pragma unroll
    for (int e = 0; e < 8; e++) vone[e] = (__bf16)1.0f;

    const int q0 = s * 64 + wid * 16;              // this wave's 16 q rows

    const bf16x8 qB0 = load8(Qp + (size_t)(q0 + m) * D_K + quad * 8);
    const bf16x8 qB1 = load8(Qp + (size_t)(q0 + m) * D_K + 32 + quad * 8);

    f32x4 oacc[4];
#pragma unroll
    for (int c = 0; c < 4; c++) oacc[c] = (f32x4){0.f, 0.f, 0.f, 0.f};
    f32x4 accL = (f32x4){0.f, 0.f, 0.f, 0.f};      // l for q = q0+quad*4+r

    stage(0, 0);
    int cur = 0;
#pragma unroll 1
    for (int t = 0; t <= s; t++) {
        __syncthreads();             // tile t's staging complete
        if (t < s) stage((t + 1) * 64, cur ^ 1);   // prefetch: in flight
                                                   // through compute below
        const bool diag = (t == s);
        const int  k0   = t * 64;
        const __bf16* Kc = &Ks[cur][0];
        const __bf16* Vc = &Vt[cur][0];

        // ---- S^T = K Q^T (rows=keys, cols=q); exp2; pack to bf16 words.
        // Lane (m,quad) produces keys {kb*16+quad*4 .. +3} for q=q0+m:
        // w0[kb] = keys {4*quad, 4*quad+1}, w1[kb] = {4*quad+2, 4*quad+3}.
        uint32_t w0[4], w1[4];
#pragma unroll
        for (int kb = 0; kb < 4; kb++) {
            const int rK = kb * 16 + m;
            const bf16x8 kfA = load8(Kc + rK * 64 + ((quad ^ (rK & 7)) * 8));
            const bf16x8 kfB = load8(Kc + rK * 64 + (((quad + 4) ^ (rK & 7)) * 8));
            f32x4 st = (f32x4){0.f, 0.f, 0.f, 0.f};
            st = MFMA16(kfA, qB0, st);
            st = MFMA16(kfB, qB1, st);
            const int q    = q0 + m;
            const int keyb = k0 + kb * 16 + quad * 4;
            float ex[4];
#pragma unroll
            for (int r = 0; r < 4; r++) {
                float e = __builtin_amdgcn_exp2f(st[r]);
                if (diag) e = (keyb + r <= q) ? e : 0.f;
                ex[r] = e;
            }
            w0[kb] = cvtpk(ex[0], ex[1]);
            w1[kb] = cvtpk(ex[2], ex[3]);
        }

        // ---- redistribute to A-fragments (keys 8*quad..+7 per lane).
        // Zip semantics, verified key-by-key:
        //   (X=w[lo], Y=w[hi]); swap32; swap16 => X=word j, Y=word j+2.
        uint32_t pa0 = w0[0], pa2 = w0[1]; swap32(pa0, pa2); swap16(pa0, pa2);
        uint32_t pa1 = w1[0], pa3 = w1[1]; swap32(pa1, pa3); swap16(pa1, pa3);
        uint32_t pb0 = w0[2], pb2 = w0[3]; swap32(pb0, pb2); swap16(pb0, pb2);
        uint32_t pb1 = w1[2], pb3 = w1[3]; swap32(pb1, pb3); swap16(pb1, pb3);
        const u32x4 ua = (u32x4){pa0, pa1, pa2, pa3};
        const u32x4 ub = (u32x4){pb0, pb1, pb2, pb3};
        const bf16x8 pfA = __builtin_bit_cast(bf16x8, ua);
        const bf16x8 pfB = __builtin_bit_cast(bf16x8, ub);

        // ---- row-sum via ones-MFMA: accL[r] = sum_k P[q=quad*4+r][k]
        accL = MFMA16(pfA, vone, accL);
        accL = MFMA16(pfB, vone, accL);

        // ---- P.V ----
#pragma unroll
        for (int c = 0; c < 4; c++) {
            const int rV = c * 16 + m;
            const bf16x8 vfA = load8(Vc + rV * 64 + ((quad ^ (rV & 7)) * 8));
            const bf16x8 vfB = load8(Vc + rV * 64 + (((quad + 4) ^ (rV & 7)) * 8));
            oacc[c] = MFMA16(pfA, vfA, oacc[c]);
            oacc[c] = MFMA16(pfB, vfB, oacc[c]);
        }
        cur ^= 1;
    }

    // ---- epilogue: l is already per-register in accL ----
#pragma unroll
    for (int r = 0; r < 4; r++) {
        const float inv = 1.f / accL[r];
        const int srow = q0 + quad * 4 + r;
#pragma unroll
        for (int c = 0; c < 4; c++) {
            const size_t o = ((size_t)(b * SEQ + srow)) * D_MODEL + h * D_K + c * 16 + m;
            Cc[o] = (__bf16)(oacc[c][r] * inv);
        }
    }
}

// ---------------------------------------------------------------------------
// Output projection: Out = Cc * Wo^T + bo (fp32).
// R15: 64x64 tile -> grid (64, 16) = 1024 blocks = 4/CU (was 64x128, 512
// blocks = 2/CU). Per wave: 32x32 output, 2x2 acc, 8 MFMA + 8 ds_read_b128
// per K-step (1:1 ratio). 16 KB LDS, ~70 VGPR -> occupancy-friendly; the
// 2-barrier latency chain is hidden by 16 waves/CU instead of 8.
// ---------------------------------------------------------------------------
__global__ __launch_bounds__(256) void oproj_kernel(
    const __bf16* __restrict__ Cc,
    const __bf16* __restrict__ Wob,
    const float* __restrict__ bo,
    float* __restrict__ Out)
{
    __shared__ alignas(16) __bf16 As[64 * 64];    // 8 KB
    __shared__ alignas(16) __bf16 Bs[64 * 64];    // 8 KB

    const int lane = threadIdx.x & 63;
    const int wid  = threadIdx.x >> 6;
    const int m    = lane & 15;
    const int quad = lane >> 4;
    const int wrow = wid >> 1, wcol = wid & 1;
    const int row0 = blockIdx.x * 64;
    const int col0 = blockIdx.y * 64;

    f32x4 acc[2][2];
#pragma unroll
    for (int i = 0; i < 2; i++)
#pragma unroll
        for (int j = 0; j < 2; j++) acc[i][j] = (f32x4){0.f, 0.f, 0.f, 0.f};

    for (int k0 = 0; k0 < D_MODEL; k0 += 64) {
#pragma unroll
        for (int i = 0; i < 2; i++) {
            const int slot = wid * 128 + i * 64 + lane;
            const int row  = slot >> 3;
            const int cg   = (slot & 7) ^ (row & 7);
            gload16(Cc + (size_t)(row0 + row) * D_MODEL + k0 + cg * 8,
                    (const char*)As + (size_t)(wid * 128 + i * 64) * 16);
            gload16(Wob + (size_t)(col0 + row) * D_MODEL + k0 + cg * 8,
                    (const char*)Bs + (size_t)(wid * 128 + i * 64) * 16);
        }
        __syncthreads();

        bf16x8 a2[2][2], b2[2][2];
#pragma unroll
        for (int ks = 0; ks < 2; ks++) {
#pragma unroll
            for (int i = 0; i < 2; i++) {
                const int rA = wrow * 32 + i * 16 + m;
                a2[ks][i] = load8(As + rA * 64 + (((ks * 4 + quad) ^ (rA & 7)) * 8));
                const int rB = wcol * 32 + i * 16 + m;
                b2[ks][i] = load8(Bs + rB * 64 + (((ks * 4 + quad) ^ (rB & 7)) * 8));
            }
        }
#pragma unroll
        for (int ks = 0; ks < 2; ks++)
#pragma unroll
            for (int i = 0; i < 2; i++)
#pragma unroll
                for (int j = 0; j < 2; j++)
                    acc[i][j] = MFMA16(a2[ks][i], b2[ks][j], acc[i][j]);
        __syncthreads();
    }

#pragma unroll
    for (int i = 0; i < 2; i++) {
#pragma unroll
        for (int r = 0; r < 4; r++) {
            const int R = row0 + wrow * 32 + i * 16 + quad * 4 + r;
#pragma unroll
            for (int j = 0; j < 2; j++) {
                const int E = col0 + wcol * 32 + j * 16 + m;
                Out[(size_t)R * D_MODEL + E] = acc[i][j][r] + bo[E];
            }
        }
    }
}

// ---------------------------------------------------------------------------
extern "C" void kernel_launch(void* const* d_in, const int* in_sizes, int n_in,
                              void* d_out, int out_size, void* d_ws, size_t ws_size,
                              hipStream_t stream) {
    const float* x  = (const float*)d_in[0];
    const float* Wq = (const float*)d_in[1];
    const float* Wk = (const float*)d_in[2];
    const float* Wv = (const float*)d_in[3];
    const float* Wo = (const float*)d_in[4];
    const float* bo = (const float*)d_in[5];
    // d_in[6] = causal mask — recomputed from indices, not read.

    const size_t elems  = (size_t)M_TOTAL * D_MODEL;   // 4194304
    const size_t welems = (size_t)D_MODEL * D_MODEL;   // 1048576
    __bf16* xb  = (__bf16*)d_ws;       // seg0: x (bf16) -> later Cc (aliased)
    __bf16* Qb  = xb + elems;
    __bf16* Kb  = Qb + elems;
    __bf16* Vtg = Kb + elems;          // [32][64][2048]  (V^T)
    __bf16* Wqb = Vtg + elems;
    __bf16* Wkb = Wqb + welems;
    __bf16* Wvb = Wkb + welems;
    __bf16* Wob = Wvb + welems;        // end: 40 MB
    __bf16* Cc  = xb;

    // 0) all fp32 -> bf16 conversions in one launch
    convert_all<<<dim3(4096), 256, 0, stream>>>(
        x, Wq, Wk, Wv, Wo, xb, Wqb, Wkb, Wvb, Wob);

    // 1) QKV projections (Q pre-scaled by 0.125*log2e)
    qkv_kernel<<<dim3(M_TOTAL / 128, 3 * D_MODEL / 128), 256, 0, stream>>>(
        xb, Wqb, Wkb, Wvb, Qb, Kb, Vtg);

    // 2) causal flash attention: one strip per block, big-first, 4 blocks/CU
    attn_kernel<<<dim3(BATCH * NUM_HEADS, 32), 256, 0, stream>>>(
        Qb, Kb, Vtg, Cc);

    // 3) output projection + bias -> fp32 out (64x64 tiles, 4 blocks/CU)
    oproj_kernel<<<dim3(M_TOTAL / 64, D_MODEL / 64), 256, 0, stream>>>(
        Cc, Wob, bo, (float*)d_out);
}

// Round 6
// 180.355 us; speedup vs baseline: 1.1053x; 1.0422x over previous
//
#include <hip/hip_runtime.h>
#include <hip/hip_bf16.h>
#include <stdint.h>

typedef __bf16 bf16x8 __attribute__((ext_vector_type(8)));
typedef __bf16 bf16x4 __attribute__((ext_vector_type(4)));
typedef float  f32x4  __attribute__((ext_vector_type(4)));
typedef unsigned int u32x4 __attribute__((ext_vector_type(4)));

#define D_MODEL 1024
#define NUM_HEADS 16
#define D_K 64
#define BATCH 2
#define SEQ 2048
#define M_TOTAL (BATCH * SEQ)   // 4096

// 0.125 (1/sqrt(64)) * log2(e): folded into Q at the qkv epilogue so the
// attention softmax is a bare exp2 (v_exp_f32), no per-element scale mul.
#define Q_SCALE 0.18033688011112042f

static __device__ __forceinline__ bf16x8 load8(const __bf16* p) {
    return *reinterpret_cast<const bf16x8*>(p);
}

#define MFMA16(a, b, c) __builtin_amdgcn_mfma_f32_16x16x32_bf16((a), (b), (c), 0, 0, 0)

// Async global->LDS, 16B per lane. LDS dest = wave-uniform base + lane*16.
static __device__ __forceinline__ void gload16(const void* g, const void* lds) {
    __builtin_amdgcn_global_load_lds(
        (const __attribute__((address_space(1))) uint32_t*)g,
        (__attribute__((address_space(3))) uint32_t*)lds,
        16, 0, 0);
}

// Pack two f32 -> one u32 of 2 bf16 (lo = first arg). No builtin on gfx950.
static __device__ __forceinline__ uint32_t cvtpk(float lo, float hi) {
    uint32_t r;
    asm("v_cvt_pk_bf16_f32 %0, %1, %2" : "=v"(r) : "v"(lo), "v"(hi));
    return r;
}
// CDNA4 zip semantics ("DST rows 2:3 <-> SRC rows 0:1", rows = 16 lanes):
//   swap32: a' = (a@q0, a@q1, b@q0, b@q1), b' = (a@q2, a@q3, b@q2, b@q3)
static __device__ __forceinline__ void swap32(uint32_t& a, uint32_t& b) {
    asm("v_permlane32_swap_b32 %0, %1" : "+v"(a), "+v"(b));
}
// swap16 ("DST odd rows <-> SRC even rows"):
//   a' = (a@q0, b@q0, a@q2, b@q2), b' = (a@q1, b@q1, a@q3, b@q3)
static __device__ __forceinline__ void swap16(uint32_t& a, uint32_t& b) {
    asm("v_permlane16_swap_b32 %0, %1" : "+v"(a), "+v"(b));
}

// ---------------------------------------------------------------------------
// One launch: x (2048 blocks) + 4 weight matrices (512 blocks each) fp32->bf16.
// ---------------------------------------------------------------------------
__global__ __launch_bounds__(256) void convert_all(
    const float* __restrict__ X,
    const float* __restrict__ Wq, const float* __restrict__ Wk,
    const float* __restrict__ Wv, const float* __restrict__ Wo,
    __bf16* __restrict__ xb,
    __bf16* __restrict__ dq, __bf16* __restrict__ dk,
    __bf16* __restrict__ dv, __bf16* __restrict__ dw)
{
    const float* src; __bf16* dst; size_t idx;
    if (blockIdx.x < 2048) {
        src = X; dst = xb;
        idx = (size_t)blockIdx.x * 256 + threadIdx.x;
    } else {
        const int wb  = blockIdx.x - 2048;
        const int sel = wb >> 9;
        src = (sel == 0) ? Wq : (sel == 1) ? Wk : (sel == 2) ? Wv : Wo;
        dst = (sel == 0) ? dq : (sel == 1) ? dk : (sel == 2) ? dv : dw;
        idx = (size_t)(wb & 511) * 256 + threadIdx.x;
    }
    const f32x4 a = *reinterpret_cast<const f32x4*>(src + idx * 8);
    const f32x4 b = *reinterpret_cast<const f32x4*>(src + idx * 8 + 4);
    bf16x8 r;
#pragma unroll
    for (int e = 0; e < 4; e++) { r[e] = (__bf16)a[e]; r[4 + e] = (__bf16)b[e]; }
    *reinterpret_cast<bf16x8*>(dst + idx * 8) = r;
}

// ---------------------------------------------------------------------------
// QKV GEMM: 128x128 tile, BK=64, swizzled gload16 staging. R16: DOUBLE-
// BUFFERED prefetch loop (T3 "minimum 2-phase"): stage(k+1) issued right
// after the barrier, in flight through compute; ONE barrier per K-step (was
// stage -> barrier -> compute -> barrier = latency fully exposed 16x).
// LDS 64 KB (2 buf x (A 16K + B 16K)) -> 2 blocks/CU. Q output pre-scaled
// by Q_SCALE. V output transposed through LDS (reuses smem after a trailing
// barrier) -> coalesced V^T. grid = (32, 24), block = 256.
// ---------------------------------------------------------------------------
__global__ __launch_bounds__(256) void qkv_kernel(
    const __bf16* __restrict__ Xb,
    const __bf16* __restrict__ Wqb,
    const __bf16* __restrict__ Wkb,
    const __bf16* __restrict__ Wvb,
    __bf16* __restrict__ Qb,
    __bf16* __restrict__ Kb,
    __bf16* __restrict__ Vtg)
{
    __shared__ alignas(16) char smem[65536];   // A[2]16K + B[2]16K; V scratch 34K
    __bf16* As0 = (__bf16*)smem;               // [2][128*64], chunk-swizzled
    __bf16* Bs0 = As0 + 2 * 128 * 64;

    const int lane = threadIdx.x & 63;
    const int wid  = threadIdx.x >> 6;
    const int m    = lane & 15;
    const int quad = lane >> 4;
    const int wrow = wid >> 1, wcol = wid & 1;
    const int row0 = blockIdx.x * 128;
    const int col0 = blockIdx.y * 128;
    const int wsel = col0 >> 10;
    const int lcol0 = col0 & 1023;

    const __bf16* W = (wsel == 0) ? Wqb : (wsel == 1) ? Wkb : Wvb;

    // staging: 128x64 A-tile + 128x64 B-tile into buffer `buf`
    auto stage = [&](int k0, int buf) {
#pragma unroll
        for (int i = 0; i < 4; i++) {
            const int slot = wid * 256 + i * 64 + lane;
            const int row  = slot >> 3;
            const int cg   = (slot & 7) ^ (row & 7);
            gload16(Xb + (size_t)(row0 + row) * D_MODEL + k0 + cg * 8,
                    (const char*)(As0 + buf * 8192) + (size_t)(wid * 256 + i * 64) * 16);
            gload16(W + (size_t)(lcol0 + row) * D_MODEL + k0 + cg * 8,
                    (const char*)(Bs0 + buf * 8192) + (size_t)(wid * 256 + i * 64) * 16);
        }
    };

    f32x4 acc[4][4];
#pragma unroll
    for (int i = 0; i < 4; i++)
#pragma unroll
        for (int j = 0; j < 4; j++) acc[i][j] = (f32x4){0.f, 0.f, 0.f, 0.f};

    stage(0, 0);
    int cur = 0;
#pragma unroll 1
    for (int k0 = 0; k0 < D_MODEL; k0 += 64) {
        __syncthreads();                       // buffer `cur` staged
        if (k0 + 64 < D_MODEL) stage(k0 + 64, cur ^ 1);   // in flight through
                                                          // compute below
        const __bf16* As = As0 + cur * 8192;
        const __bf16* Bs = Bs0 + cur * 8192;

        bf16x8 a2[2][4], b2[2][4];
#pragma unroll
        for (int ks = 0; ks < 2; ks++) {
#pragma unroll
            for (int i = 0; i < 4; i++) {
                const int rA = wrow * 64 + i * 16 + m;
                a2[ks][i] = load8(As + rA * 64 + (((ks * 4 + quad) ^ (rA & 7)) * 8));
                const int rB = wcol * 64 + i * 16 + m;
                b2[ks][i] = load8(Bs + rB * 64 + (((ks * 4 + quad) ^ (rB & 7)) * 8));
            }
        }
#pragma unroll
        for (int ks = 0; ks < 2; ks++)
#pragma unroll
            for (int i = 0; i < 4; i++)
#pragma unroll
                for (int j = 0; j < 4; j++)
                    acc[i][j] = MFMA16(a2[ks][i], b2[ks][j], acc[i][j]);
        cur ^= 1;
    }
    __syncthreads();   // all LDS reads done before V-path smem reuse

    if (wsel < 2) {
        // Q (pre-scaled) / K: [bh][s][dk]
        __bf16* Out = wsel ? Kb : Qb;
        const float sc = wsel ? 1.f : Q_SCALE;
#pragma unroll
        for (int i = 0; i < 4; i++) {
#pragma unroll
            for (int r = 0; r < 4; r++) {
                const int R  = row0 + wrow * 64 + i * 16 + quad * 4 + r;
                const int bb = R >> 11;
                const int s  = R & (SEQ - 1);
#pragma unroll
                for (int j = 0; j < 4; j++) {
                    const int e  = lcol0 + wcol * 64 + j * 16 + m;
                    const int h  = e >> 6;
                    const int dk = e & (D_K - 1);
                    Out[((size_t)(bb * NUM_HEADS + h) * SEQ + s) * D_K + dk] =
                        (__bf16)(acc[i][j][r] * sc);
                }
            }
        }
    } else {
        // V: transpose tile through LDS, store coalesced V^T rows.
        __bf16* Ls = (__bf16*)smem;   // [128][136]
#pragma unroll
        for (int i = 0; i < 4; i++)
#pragma unroll
            for (int r = 0; r < 4; r++)
#pragma unroll
                for (int j = 0; j < 4; j++)
                    Ls[(wcol * 64 + j * 16 + m) * 136 +
                       wrow * 64 + i * 16 + quad * 4 + r] = (__bf16)acc[i][j][r];
        __syncthreads();
        const int bb   = row0 >> 11;
        const int sloc = row0 & (SEQ - 1);
#pragma unroll
        for (int i = 0; i < 8; i++) {
            const int c   = i * 256 + threadIdx.x;
            const int dkl = c >> 4;
            const int sc  = c & 15;
            const bf16x8 v = load8(Ls + dkl * 136 + sc * 8);
            const int e  = lcol0 + dkl;
            const int h  = e >> 6;
            const int dk = e & (D_K - 1);
            const int bh = bb * NUM_HEADS + h;
            *reinterpret_cast<bf16x8*>(
                Vtg + ((size_t)bh * D_K + dk) * SEQ + sloc + sc * 8) = v;
        }
    }
}

// ---------------------------------------------------------------------------
// Flash attention, causal, ONE STRIP PER BLOCK + DOUBLE-BUFFERED LDS staging.
// R13/R15 configuration (best verified): QBLK=64, grid (32 bh, 32 strips),
// 1024 blocks = 4/CU, big strips first. Register-resident P (zip-permlane),
// ones-MFMA row sums.
// ---------------------------------------------------------------------------
__global__ __launch_bounds__(256) void attn_kernel(
    const __bf16* __restrict__ Qb,
    const __bf16* __restrict__ Kb,
    const __bf16* __restrict__ Vtg,
    __bf16* __restrict__ Cc)
{
    __shared__ alignas(16) __bf16 Ks[2][64 * 64];  // ping-pong, 16 KB
    __shared__ alignas(16) __bf16 Vt[2][64 * 64];  // ping-pong, 16 KB

    const int lane = threadIdx.x & 63;
    const int wid  = threadIdx.x >> 6;
    const int m    = lane & 15;
    const int quad = lane >> 4;
    const int bh   = blockIdx.x;
    const int b    = bh >> 4;
    const int h    = bh & (NUM_HEADS - 1);
    const int s    = 31 - blockIdx.y;              // strip index, big first

    const __bf16* Qp = Qb  + (size_t)bh * SEQ * D_K;
    const __bf16* Kp = Kb  + (size_t)bh * SEQ * D_K;
    const __bf16* Vp = Vtg + (size_t)bh * D_K * SEQ;

    // staging lambda: 64x64 K tile + 64x64 V^T tile into buffer `buf`
    auto stage = [&](int k0, int buf) {
#pragma unroll
        for (int i = 0; i < 2; i++) {
            const int slot = wid * 128 + i * 64 + lane;
            const int row  = slot >> 3;
            const int cg   = (slot & 7) ^ (row & 7);
            gload16(Kp + (size_t)(k0 + row) * D_K + cg * 8,
                    (const char*)&Ks[buf][0] + (size_t)(wid * 128 + i * 64) * 16);
            gload16(Vp + (size_t)row * SEQ + k0 + cg * 8,
                    (const char*)&Vt[buf][0] + (size_t)(wid * 128 + i * 64) * 16);
        }
    };

    bf16x8 vone;
#pragma unroll
    for (int e = 0; e < 8; e++) vone[e] = (__bf16)1.0f;

    const int q0 = s * 64 + wid * 16;              // this wave's 16 q rows

    const bf16x8 qB0 = load8(Qp + (size_t)(q0 + m) * D_K + quad * 8);
    const bf16x8 qB1 = load8(Qp + (size_t)(q0 + m) * D_K + 32 + quad * 8);

    f32x4 oacc[4];
#pragma unroll
    for (int c = 0; c < 4; c++) oacc[c] = (f32x4){0.f, 0.f, 0.f, 0.f};
    f32x4 accL = (f32x4){0.f, 0.f, 0.f, 0.f};      // l for q = q0+quad*4+r

    stage(0, 0);
    int cur = 0;
#pragma unroll 1
    for (int t = 0; t <= s; t++) {
        __syncthreads();             // tile t's staging complete
        if (t < s) stage((t + 1) * 64, cur ^ 1);   // prefetch: in flight
                                                   // through compute below
        const bool diag = (t == s);
        const int  k0   = t * 64;
        const __bf16* Kc = &Ks[cur][0];
        const __bf16* Vc = &Vt[cur][0];

        // ---- S^T = K Q^T (rows=keys, cols=q); exp2; pack to bf16 words.
        // Lane (m,quad) produces keys {kb*16+quad*4 .. +3} for q=q0+m:
        // w0[kb] = keys {4*quad, 4*quad+1}, w1[kb] = {4*quad+2, 4*quad+3}.
        uint32_t w0[4], w1[4];
#pragma unroll
        for (int kb = 0; kb < 4; kb++) {
            const int rK = kb * 16 + m;
            const bf16x8 kfA = load8(Kc + rK * 64 + ((quad ^ (rK & 7)) * 8));
            const bf16x8 kfB = load8(Kc + rK * 64 + (((quad + 4) ^ (rK & 7)) * 8));
            f32x4 st = (f32x4){0.f, 0.f, 0.f, 0.f};
            st = MFMA16(kfA, qB0, st);
            st = MFMA16(kfB, qB1, st);
            const int q    = q0 + m;
            const int keyb = k0 + kb * 16 + quad * 4;
            float ex[4];
#pragma unroll
            for (int r = 0; r < 4; r++) {
                float e = __builtin_amdgcn_exp2f(st[r]);
                if (diag) e = (keyb + r <= q) ? e : 0.f;
                ex[r] = e;
            }
            w0[kb] = cvtpk(ex[0], ex[1]);
            w1[kb] = cvtpk(ex[2], ex[3]);
        }

        // ---- redistribute to A-fragments (keys 8*quad..+7 per lane).
        // Zip semantics, verified key-by-key:
        //   (X=w[lo], Y=w[hi]); swap32; swap16 => X=word j, Y=word j+2.
        uint32_t pa0 = w0[0], pa2 = w0[1]; swap32(pa0, pa2); swap16(pa0, pa2);
        uint32_t pa1 = w1[0], pa3 = w1[1]; swap32(pa1, pa3); swap16(pa1, pa3);
        uint32_t pb0 = w0[2], pb2 = w0[3]; swap32(pb0, pb2); swap16(pb0, pb2);
        uint32_t pb1 = w1[2], pb3 = w1[3]; swap32(pb1, pb3); swap16(pb1, pb3);
        const u32x4 ua = (u32x4){pa0, pa1, pa2, pa3};
        const u32x4 ub = (u32x4){pb0, pb1, pb2, pb3};
        const bf16x8 pfA = __builtin_bit_cast(bf16x8, ua);
        const bf16x8 pfB = __builtin_bit_cast(bf16x8, ub);

        // ---- row-sum via ones-MFMA: accL[r] = sum_k P[q=quad*4+r][k]
        accL = MFMA16(pfA, vone, accL);
        accL = MFMA16(pfB, vone, accL);

        // ---- P.V ----
#pragma unroll
        for (int c = 0; c < 4; c++) {
            const int rV = c * 16 + m;
            const bf16x8 vfA = load8(Vc + rV * 64 + ((quad ^ (rV & 7)) * 8));
            const bf16x8 vfB = load8(Vc + rV * 64 + (((quad + 4) ^ (rV & 7)) * 8));
            oacc[c] = MFMA16(pfA, vfA, oacc[c]);
            oacc[c] = MFMA16(pfB, vfB, oacc[c]);
        }
        cur ^= 1;
    }

    // ---- epilogue: l is already per-register in accL ----
#pragma unroll
    for (int r = 0; r < 4; r++) {
        const float inv = 1.f / accL[r];
        const int srow = q0 + quad * 4 + r;
#pragma unroll
        for (int c = 0; c < 4; c++) {
            const size_t o = ((size_t)(b * SEQ + srow)) * D_MODEL + h * D_K + c * 16 + m;
            Cc[o] = (__bf16)(oacc[c][r] * inv);
        }
    }
}

// ---------------------------------------------------------------------------
// Output projection: Out = Cc * Wo^T + bo (fp32). 64x64 tile, grid (64,16)
// = 1024 blocks = 4/CU. R16: double-buffered prefetch loop (same T3
// minimum-2-phase as qkv): one barrier per K-step, next tile's staging in
// flight through compute. LDS 32 KB -> still 4 blocks/CU.
// ---------------------------------------------------------------------------
__global__ __launch_bounds__(256) void oproj_kernel(
    const __bf16* __restrict__ Cc,
    const __bf16* __restrict__ Wob,
    const float* __restrict__ bo,
    float* __restrict__ Out)
{
    __shared__ alignas(16) __bf16 As[2][64 * 64];  // ping-pong, 8 KB each
    __shared__ alignas(16) __bf16 Bs[2][64 * 64];  // ping-pong, 8 KB each

    const int lane = threadIdx.x & 63;
    const int wid  = threadIdx.x >> 6;
    const int m    = lane & 15;
    const int quad = lane >> 4;
    const int wrow = wid >> 1, wcol = wid & 1;
    const int row0 = blockIdx.x * 64;
    const int col0 = blockIdx.y * 64;

    auto stage = [&](int k0, int buf) {
#pragma unroll
        for (int i = 0; i < 2; i++) {
            const int slot = wid * 128 + i * 64 + lane;
            const int row  = slot >> 3;
            const int cg   = (slot & 7) ^ (row & 7);
            gload16(Cc + (size_t)(row0 + row) * D_MODEL + k0 + cg * 8,
                    (const char*)&As[buf][0] + (size_t)(wid * 128 + i * 64) * 16);
            gload16(Wob + (size_t)(col0 + row) * D_MODEL + k0 + cg * 8,
                    (const char*)&Bs[buf][0] + (size_t)(wid * 128 + i * 64) * 16);
        }
    };

    f32x4 acc[2][2];
#pragma unroll
    for (int i = 0; i < 2; i++)
#pragma unroll
        for (int j = 0; j < 2; j++) acc[i][j] = (f32x4){0.f, 0.f, 0.f, 0.f};

    stage(0, 0);
    int cur = 0;
#pragma unroll 1
    for (int k0 = 0; k0 < D_MODEL; k0 += 64) {
        __syncthreads();                       // buffer `cur` staged
        if (k0 + 64 < D_MODEL) stage(k0 + 64, cur ^ 1);

        bf16x8 a2[2][2], b2[2][2];
#pragma unroll
        for (int ks = 0; ks < 2; ks++) {
#pragma unroll
            for (int i = 0; i < 2; i++) {
                const int rA = wrow * 32 + i * 16 + m;
                a2[ks][i] = load8(&As[cur][0] + rA * 64 + (((ks * 4 + quad) ^ (rA & 7)) * 8));
                const int rB = wcol * 32 + i * 16 + m;
                b2[ks][i] = load8(&Bs[cur][0] + rB * 64 + (((ks * 4 + quad) ^ (rB & 7)) * 8));
            }
        }
#pragma unroll
        for (int ks = 0; ks < 2; ks++)
#pragma unroll
            for (int i = 0; i < 2; i++)
#pragma unroll
                for (int j = 0; j < 2; j++)
                    acc[i][j] = MFMA16(a2[ks][i], b2[ks][j], acc[i][j]);
        cur ^= 1;
    }

#pragma unroll
    for (int i = 0; i < 2; i++) {
#pragma unroll
        for (int r = 0; r < 4; r++) {
            const int R = row0 + wrow * 32 + i * 16 + quad * 4 + r;
#pragma unroll
            for (int j = 0; j < 2; j++) {
                const int E = col0 + wcol * 32 + j * 16 + m;
                Out[(size_t)R * D_MODEL + E] = acc[i][j][r] + bo[E];
            }
        }
    }
}

// ---------------------------------------------------------------------------
extern "C" void kernel_launch(void* const* d_in, const int* in_sizes, int n_in,
                              void* d_out, int out_size, void* d_ws, size_t ws_size,
                              hipStream_t stream) {
    const float* x  = (const float*)d_in[0];
    const float* Wq = (const float*)d_in[1];
    const float* Wk = (const float*)d_in[2];
    const float* Wv = (const float*)d_in[3];
    const float* Wo = (const float*)d_in[4];
    const float* bo = (const float*)d_in[5];
    // d_in[6] = causal mask — recomputed from indices, not read.

    const size_t elems  = (size_t)M_TOTAL * D_MODEL;   // 4194304
    const size_t welems = (size_t)D_MODEL * D_MODEL;   // 1048576
    __bf16* xb  = (__bf16*)d_ws;       // seg0: x (bf16) -> later Cc (aliased)
    __bf16* Qb  = xb + elems;
    __bf16* Kb  = Qb + elems;
    __bf16* Vtg = Kb + elems;          // [32][64][2048]  (V^T)
    __bf16* Wqb = Vtg + elems;
    __bf16* Wkb = Wqb + welems;
    __bf16* Wvb = Wkb + welems;
    __bf16* Wob = Wvb + welems;        // end: 40 MB
    __bf16* Cc  = xb;

    // 0) all fp32 -> bf16 conversions in one launch
    convert_all<<<dim3(4096), 256, 0, stream>>>(
        x, Wq, Wk, Wv, Wo, xb, Wqb, Wkb, Wvb, Wob);

    // 1) QKV projections (Q pre-scaled by 0.125*log2e), dbuf prefetch loop
    qkv_kernel<<<dim3(M_TOTAL / 128, 3 * D_MODEL / 128), 256, 0, stream>>>(
        xb, Wqb, Wkb, Wvb, Qb, Kb, Vtg);

    // 2) causal flash attention: one strip per block, big-first, 4 blocks/CU
    attn_kernel<<<dim3(BATCH * NUM_HEADS, 32), 256, 0, stream>>>(
        Qb, Kb, Vtg, Cc);

    // 3) output projection + bias -> fp32 out (64x64 tiles, dbuf prefetch)
    oproj_kernel<<<dim3(M_TOTAL / 64, D_MODEL / 64), 256, 0, stream>>>(
        Cc, Wob, bo, (float*)d_out);
}

// Round 7
// 179.300 us; speedup vs baseline: 1.1118x; 1.0059x over previous
//
#include <hip/hip_runtime.h>
#include <hip/hip_bf16.h>
#include <stdint.h>

typedef __bf16 bf16x8 __attribute__((ext_vector_type(8)));
typedef __bf16 bf16x4 __attribute__((ext_vector_type(4)));
typedef float  f32x4  __attribute__((ext_vector_type(4)));
typedef unsigned int u32x4 __attribute__((ext_vector_type(4)));

#define D_MODEL 1024
#define NUM_HEADS 16
#define D_K 64
#define BATCH 2
#define SEQ 2048
#define M_TOTAL (BATCH * SEQ)   // 4096

// 0.125 (1/sqrt(64)) * log2(e): folded into Q at the qkv epilogue so the
// attention softmax is a bare exp2 (v_exp_f32), no per-element scale mul.
#define Q_SCALE 0.18033688011112042f

static __device__ __forceinline__ bf16x8 load8(const __bf16* p) {
    return *reinterpret_cast<const bf16x8*>(p);
}

#define MFMA16(a, b, c) __builtin_amdgcn_mfma_f32_16x16x32_bf16((a), (b), (c), 0, 0, 0)

// Async global->LDS, 16B per lane. LDS dest = wave-uniform base + lane*16.
static __device__ __forceinline__ void gload16(const void* g, const void* lds) {
    __builtin_amdgcn_global_load_lds(
        (const __attribute__((address_space(1))) uint32_t*)g,
        (__attribute__((address_space(3))) uint32_t*)lds,
        16, 0, 0);
}

// Pack two f32 -> one u32 of 2 bf16 (lo = first arg). No builtin on gfx950.
static __device__ __forceinline__ uint32_t cvtpk(float lo, float hi) {
    uint32_t r;
    asm("v_cvt_pk_bf16_f32 %0, %1, %2" : "=v"(r) : "v"(lo), "v"(hi));
    return r;
}
// CDNA4 zip semantics ("DST rows 2:3 <-> SRC rows 0:1", rows = 16 lanes):
//   swap32: a' = (a@q0, a@q1, b@q0, b@q1), b' = (a@q2, a@q3, b@q2, b@q3)
static __device__ __forceinline__ void swap32(uint32_t& a, uint32_t& b) {
    asm("v_permlane32_swap_b32 %0, %1" : "+v"(a), "+v"(b));
}
// swap16 ("DST odd rows <-> SRC even rows"):
//   a' = (a@q0, b@q0, a@q2, b@q2), b' = (a@q1, b@q1, a@q3, b@q3)
static __device__ __forceinline__ void swap16(uint32_t& a, uint32_t& b) {
    asm("v_permlane16_swap_b32 %0, %1" : "+v"(a), "+v"(b));
}

// ---------------------------------------------------------------------------
// One launch: x (2048 blocks) + 4 weight matrices (512 blocks each) fp32->bf16.
// ---------------------------------------------------------------------------
__global__ __launch_bounds__(256) void convert_all(
    const float* __restrict__ X,
    const float* __restrict__ Wq, const float* __restrict__ Wk,
    const float* __restrict__ Wv, const float* __restrict__ Wo,
    __bf16* __restrict__ xb,
    __bf16* __restrict__ dq, __bf16* __restrict__ dk,
    __bf16* __restrict__ dv, __bf16* __restrict__ dw)
{
    const float* src; __bf16* dst; size_t idx;
    if (blockIdx.x < 2048) {
        src = X; dst = xb;
        idx = (size_t)blockIdx.x * 256 + threadIdx.x;
    } else {
        const int wb  = blockIdx.x - 2048;
        const int sel = wb >> 9;
        src = (sel == 0) ? Wq : (sel == 1) ? Wk : (sel == 2) ? Wv : Wo;
        dst = (sel == 0) ? dq : (sel == 1) ? dk : (sel == 2) ? dv : dw;
        idx = (size_t)(wb & 511) * 256 + threadIdx.x;
    }
    const f32x4 a = *reinterpret_cast<const f32x4*>(src + idx * 8);
    const f32x4 b = *reinterpret_cast<const f32x4*>(src + idx * 8 + 4);
    bf16x8 r;
#pragma unroll
    for (int e = 0; e < 4; e++) { r[e] = (__bf16)a[e]; r[4 + e] = (__bf16)b[e]; }
    *reinterpret_cast<bf16x8*>(dst + idx * 8) = r;
}

// ---------------------------------------------------------------------------
// QKV GEMM: 128x128 tile, BK=64, swizzled gload16 staging, double-buffered
// prefetch loop (one barrier per K-step, next tile's loads in flight through
// compute). LDS 64 KB -> 2 blocks/CU. Q output pre-scaled by Q_SCALE.
// V output transposed through LDS -> coalesced V^T. grid = (32, 24).
// ---------------------------------------------------------------------------
__global__ __launch_bounds__(256) void qkv_kernel(
    const __bf16* __restrict__ Xb,
    const __bf16* __restrict__ Wqb,
    const __bf16* __restrict__ Wkb,
    const __bf16* __restrict__ Wvb,
    __bf16* __restrict__ Qb,
    __bf16* __restrict__ Kb,
    __bf16* __restrict__ Vtg)
{
    __shared__ alignas(16) char smem[65536];   // A[2]16K + B[2]16K; V scratch 34K
    __bf16* As0 = (__bf16*)smem;               // [2][128*64], chunk-swizzled
    __bf16* Bs0 = As0 + 2 * 128 * 64;

    const int lane = threadIdx.x & 63;
    const int wid  = threadIdx.x >> 6;
    const int m    = lane & 15;
    const int quad = lane >> 4;
    const int wrow = wid >> 1, wcol = wid & 1;
    const int row0 = blockIdx.x * 128;
    const int col0 = blockIdx.y * 128;
    const int wsel = col0 >> 10;
    const int lcol0 = col0 & 1023;

    const __bf16* W = (wsel == 0) ? Wqb : (wsel == 1) ? Wkb : Wvb;

    // staging: 128x64 A-tile + 128x64 B-tile into buffer `buf`
    auto stage = [&](int k0, int buf) {
#pragma unroll
        for (int i = 0; i < 4; i++) {
            const int slot = wid * 256 + i * 64 + lane;
            const int row  = slot >> 3;
            const int cg   = (slot & 7) ^ (row & 7);
            gload16(Xb + (size_t)(row0 + row) * D_MODEL + k0 + cg * 8,
                    (const char*)(As0 + buf * 8192) + (size_t)(wid * 256 + i * 64) * 16);
            gload16(W + (size_t)(lcol0 + row) * D_MODEL + k0 + cg * 8,
                    (const char*)(Bs0 + buf * 8192) + (size_t)(wid * 256 + i * 64) * 16);
        }
    };

    f32x4 acc[4][4];
#pragma unroll
    for (int i = 0; i < 4; i++)
#pragma unroll
        for (int j = 0; j < 4; j++) acc[i][j] = (f32x4){0.f, 0.f, 0.f, 0.f};

    stage(0, 0);
    int cur = 0;
#pragma unroll 1
    for (int k0 = 0; k0 < D_MODEL; k0 += 64) {
        __syncthreads();                       // buffer `cur` staged
        if (k0 + 64 < D_MODEL) stage(k0 + 64, cur ^ 1);   // in flight through
                                                          // compute below
        const __bf16* As = As0 + cur * 8192;
        const __bf16* Bs = Bs0 + cur * 8192;

        bf16x8 a2[2][4], b2[2][4];
#pragma unroll
        for (int ks = 0; ks < 2; ks++) {
#pragma unroll
            for (int i = 0; i < 4; i++) {
                const int rA = wrow * 64 + i * 16 + m;
                a2[ks][i] = load8(As + rA * 64 + (((ks * 4 + quad) ^ (rA & 7)) * 8));
                const int rB = wcol * 64 + i * 16 + m;
                b2[ks][i] = load8(Bs + rB * 64 + (((ks * 4 + quad) ^ (rB & 7)) * 8));
            }
        }
#pragma unroll
        for (int ks = 0; ks < 2; ks++)
#pragma unroll
            for (int i = 0; i < 4; i++)
#pragma unroll
                for (int j = 0; j < 4; j++)
                    acc[i][j] = MFMA16(a2[ks][i], b2[ks][j], acc[i][j]);
        cur ^= 1;
    }
    __syncthreads();   // all LDS reads done before V-path smem reuse

    if (wsel < 2) {
        // Q (pre-scaled) / K: [bh][s][dk]
        __bf16* Out = wsel ? Kb : Qb;
        const float sc = wsel ? 1.f : Q_SCALE;
#pragma unroll
        for (int i = 0; i < 4; i++) {
#pragma unroll
            for (int r = 0; r < 4; r++) {
                const int R  = row0 + wrow * 64 + i * 16 + quad * 4 + r;
                const int bb = R >> 11;
                const int s  = R & (SEQ - 1);
#pragma unroll
                for (int j = 0; j < 4; j++) {
                    const int e  = lcol0 + wcol * 64 + j * 16 + m;
                    const int h  = e >> 6;
                    const int dk = e & (D_K - 1);
                    Out[((size_t)(bb * NUM_HEADS + h) * SEQ + s) * D_K + dk] =
                        (__bf16)(acc[i][j][r] * sc);
                }
            }
        }
    } else {
        // V: transpose tile through LDS, store coalesced V^T rows.
        __bf16* Ls = (__bf16*)smem;   // [128][136]
#pragma unroll
        for (int i = 0; i < 4; i++)
#pragma unroll
            for (int r = 0; r < 4; r++)
#pragma unroll
                for (int j = 0; j < 4; j++)
                    Ls[(wcol * 64 + j * 16 + m) * 136 +
                       wrow * 64 + i * 16 + quad * 4 + r] = (__bf16)acc[i][j][r];
        __syncthreads();
        const int bb   = row0 >> 11;
        const int sloc = row0 & (SEQ - 1);
#pragma unroll
        for (int i = 0; i < 8; i++) {
            const int c   = i * 256 + threadIdx.x;
            const int dkl = c >> 4;
            const int sc  = c & 15;
            const bf16x8 v = load8(Ls + dkl * 136 + sc * 8);
            const int e  = lcol0 + dkl;
            const int h  = e >> 6;
            const int dk = e & (D_K - 1);
            const int bh = bb * NUM_HEADS + h;
            *reinterpret_cast<bf16x8*>(
                Vtg + ((size_t)bh * D_K + dk) * SEQ + sloc + sc * 8) = v;
        }
    }
}

// ---------------------------------------------------------------------------
// Flash attention, causal, ONE STRIP PER BLOCK + DOUBLE-BUFFERED LDS staging.
// QBLK=64, grid (32 bh, 32 strips), 1024 blocks = 4/CU.
// R17: BALANCED strip permutation. With s=31-y, round-robin dispatch gave CU
// group k the strips {31-k, 23-k, 15-k, 7-k} -> 80 vs 48 tiles/CU (1.67x
// imbalance; measured OccupancyPercent 23%). New map: for o = y&7,
// s(y) = {31-o, o, 23-o, 8+o} by group g=y>>3 -> every CU sums to 62+4 = 66
// tiles exactly; big strips still dispatch first.
// R17b: s_setprio(1) around MFMA clusters (T5; +4-7% attn with independent
// blocks per CU, m191).
// Register-resident P (zip-permlane), ones-MFMA row sums.
// ---------------------------------------------------------------------------
__global__ __launch_bounds__(256) void attn_kernel(
    const __bf16* __restrict__ Qb,
    const __bf16* __restrict__ Kb,
    const __bf16* __restrict__ Vtg,
    __bf16* __restrict__ Cc)
{
    __shared__ alignas(16) __bf16 Ks[2][64 * 64];  // ping-pong, 16 KB
    __shared__ alignas(16) __bf16 Vt[2][64 * 64];  // ping-pong, 16 KB

    const int lane = threadIdx.x & 63;
    const int wid  = threadIdx.x >> 6;
    const int m    = lane & 15;
    const int quad = lane >> 4;
    const int bh   = blockIdx.x;
    const int b    = bh >> 4;
    const int h    = bh & (NUM_HEADS - 1);
    // balanced strip map: per-CU strip-length sums are equal (see header)
    const int y    = blockIdx.y;
    const int g    = y >> 3;
    const int o    = y & 7;
    const int s    = (g == 0) ? 31 - o : (g == 1) ? o : (g == 2) ? 23 - o : 8 + o;

    const __bf16* Qp = Qb  + (size_t)bh * SEQ * D_K;
    const __bf16* Kp = Kb  + (size_t)bh * SEQ * D_K;
    const __bf16* Vp = Vtg + (size_t)bh * D_K * SEQ;

    // staging lambda: 64x64 K tile + 64x64 V^T tile into buffer `buf`
    auto stage = [&](int k0, int buf) {
#pragma unroll
        for (int i = 0; i < 2; i++) {
            const int slot = wid * 128 + i * 64 + lane;
            const int row  = slot >> 3;
            const int cg   = (slot & 7) ^ (row & 7);
            gload16(Kp + (size_t)(k0 + row) * D_K + cg * 8,
                    (const char*)&Ks[buf][0] + (size_t)(wid * 128 + i * 64) * 16);
            gload16(Vp + (size_t)row * SEQ + k0 + cg * 8,
                    (const char*)&Vt[buf][0] + (size_t)(wid * 128 + i * 64) * 16);
        }
    };

    bf16x8 vone;
#pragma unroll
    for (int e = 0; e < 8; e++) vone[e] = (__bf16)1.0f;

    const int q0 = s * 64 + wid * 16;              // this wave's 16 q rows

    const bf16x8 qB0 = load8(Qp + (size_t)(q0 + m) * D_K + quad * 8);
    const bf16x8 qB1 = load8(Qp + (size_t)(q0 + m) * D_K + 32 + quad * 8);

    f32x4 oacc[4];
#pragma unroll
    for (int c = 0; c < 4; c++) oacc[c] = (f32x4){0.f, 0.f, 0.f, 0.f};
    f32x4 accL = (f32x4){0.f, 0.f, 0.f, 0.f};      // l for q = q0+quad*4+r

    stage(0, 0);
    int cur = 0;
#pragma unroll 1
    for (int t = 0; t <= s; t++) {
        __syncthreads();             // tile t's staging complete
        if (t < s) stage((t + 1) * 64, cur ^ 1);   // prefetch: in flight
                                                   // through compute below
        const bool diag = (t == s);
        const int  k0   = t * 64;
        const __bf16* Kc = &Ks[cur][0];
        const __bf16* Vc = &Vt[cur][0];

        // ---- S^T = K Q^T (rows=keys, cols=q); exp2; pack to bf16 words.
        // Lane (m,quad) produces keys {kb*16+quad*4 .. +3} for q=q0+m:
        // w0[kb] = keys {4*quad, 4*quad+1}, w1[kb] = {4*quad+2, 4*quad+3}.
        uint32_t w0[4], w1[4];
#pragma unroll
        for (int kb = 0; kb < 4; kb++) {
            const int rK = kb * 16 + m;
            const bf16x8 kfA = load8(Kc + rK * 64 + ((quad ^ (rK & 7)) * 8));
            const bf16x8 kfB = load8(Kc + rK * 64 + (((quad + 4) ^ (rK & 7)) * 8));
            f32x4 st = (f32x4){0.f, 0.f, 0.f, 0.f};
            __builtin_amdgcn_s_setprio(1);
            st = MFMA16(kfA, qB0, st);
            st = MFMA16(kfB, qB1, st);
            __builtin_amdgcn_s_setprio(0);
            const int q    = q0 + m;
            const int keyb = k0 + kb * 16 + quad * 4;
            float ex[4];
#pragma unroll
            for (int r = 0; r < 4; r++) {
                float e = __builtin_amdgcn_exp2f(st[r]);
                if (diag) e = (keyb + r <= q) ? e : 0.f;
                ex[r] = e;
            }
            w0[kb] = cvtpk(ex[0], ex[1]);
            w1[kb] = cvtpk(ex[2], ex[3]);
        }

        // ---- redistribute to A-fragments (keys 8*quad..+7 per lane).
        // Zip semantics, verified key-by-key:
        //   (X=w[lo], Y=w[hi]); swap32; swap16 => X=word j, Y=word j+2.
        uint32_t pa0 = w0[0], pa2 = w0[1]; swap32(pa0, pa2); swap16(pa0, pa2);
        uint32_t pa1 = w1[0], pa3 = w1[1]; swap32(pa1, pa3); swap16(pa1, pa3);
        uint32_t pb0 = w0[2], pb2 = w0[3]; swap32(pb0, pb2); swap16(pb0, pb2);
        uint32_t pb1 = w1[2], pb3 = w1[3]; swap32(pb1, pb3); swap16(pb1, pb3);
        const u32x4 ua = (u32x4){pa0, pa1, pa2, pa3};
        const u32x4 ub = (u32x4){pb0, pb1, pb2, pb3};
        const bf16x8 pfA = __builtin_bit_cast(bf16x8, ua);
        const bf16x8 pfB = __builtin_bit_cast(bf16x8, ub);

        // ---- row-sum via ones-MFMA + P.V (MFMA cluster, setprio-wrapped) --
        __builtin_amdgcn_s_setprio(1);
        accL = MFMA16(pfA, vone, accL);
        accL = MFMA16(pfB, vone, accL);
#pragma unroll
        for (int c = 0; c < 4; c++) {
            const int rV = c * 16 + m;
            const bf16x8 vfA = load8(Vc + rV * 64 + ((quad ^ (rV & 7)) * 8));
            const bf16x8 vfB = load8(Vc + rV * 64 + (((quad + 4) ^ (rV & 7)) * 8));
            oacc[c] = MFMA16(pfA, vfA, oacc[c]);
            oacc[c] = MFMA16(pfB, vfB, oacc[c]);
        }
        __builtin_amdgcn_s_setprio(0);
        cur ^= 1;
    }

    // ---- epilogue: l is already per-register in accL ----
#pragma unroll
    for (int r = 0; r < 4; r++) {
        const float inv = 1.f / accL[r];
        const int srow = q0 + quad * 4 + r;
#pragma unroll
        for (int c = 0; c < 4; c++) {
            const size_t o2 = ((size_t)(b * SEQ + srow)) * D_MODEL + h * D_K + c * 16 + m;
            Cc[o2] = (__bf16)(oacc[c][r] * inv);
        }
    }
}

// ---------------------------------------------------------------------------
// Output projection: Out = Cc * Wo^T + bo (fp32). 64x64 tile, grid (64,16)
// = 1024 blocks = 4/CU, double-buffered prefetch loop (one barrier/K-step).
// ---------------------------------------------------------------------------
__global__ __launch_bounds__(256) void oproj_kernel(
    const __bf16* __restrict__ Cc,
    const __bf16* __restrict__ Wob,
    const float* __restrict__ bo,
    float* __restrict__ Out)
{
    __shared__ alignas(16) __bf16 As[2][64 * 64];  // ping-pong, 8 KB each
    __shared__ alignas(16) __bf16 Bs[2][64 * 64];  // ping-pong, 8 KB each

    const int lane = threadIdx.x & 63;
    const int wid  = threadIdx.x >> 6;
    const int m    = lane & 15;
    const int quad = lane >> 4;
    const int wrow = wid >> 1, wcol = wid & 1;
    const int row0 = blockIdx.x * 64;
    const int col0 = blockIdx.y * 64;

    auto stage = [&](int k0, int buf) {
#pragma unroll
        for (int i = 0; i < 2; i++) {
            const int slot = wid * 128 + i * 64 + lane;
            const int row  = slot >> 3;
            const int cg   = (slot & 7) ^ (row & 7);
            gload16(Cc + (size_t)(row0 + row) * D_MODEL + k0 + cg * 8,
                    (const char*)&As[buf][0] + (size_t)(wid * 128 + i * 64) * 16);
            gload16(Wob + (size_t)(col0 + row) * D_MODEL + k0 + cg * 8,
                    (const char*)&Bs[buf][0] + (size_t)(wid * 128 + i * 64) * 16);
        }
    };

    f32x4 acc[2][2];
#pragma unroll
    for (int i = 0; i < 2; i++)
#pragma unroll
        for (int j = 0; j < 2; j++) acc[i][j] = (f32x4){0.f, 0.f, 0.f, 0.f};

    stage(0, 0);
    int cur = 0;
#pragma unroll 1
    for (int k0 = 0; k0 < D_MODEL; k0 += 64) {
        __syncthreads();                       // buffer `cur` staged
        if (k0 + 64 < D_MODEL) stage(k0 + 64, cur ^ 1);

        bf16x8 a2[2][2], b2[2][2];
#pragma unroll
        for (int ks = 0; ks < 2; ks++) {
#pragma unroll
            for (int i = 0; i < 2; i++) {
                const int rA = wrow * 32 + i * 16 + m;
                a2[ks][i] = load8(&As[cur][0] + rA * 64 + (((ks * 4 + quad) ^ (rA & 7)) * 8));
                const int rB = wcol * 32 + i * 16 + m;
                b2[ks][i] = load8(&Bs[cur][0] + rB * 64 + (((ks * 4 + quad) ^ (rB & 7)) * 8));
            }
        }
#pragma unroll
        for (int ks = 0; ks < 2; ks++)
#pragma unroll
            for (int i = 0; i < 2; i++)
#pragma unroll
                for (int j = 0; j < 2; j++)
                    acc[i][j] = MFMA16(a2[ks][i], b2[ks][j], acc[i][j]);
        cur ^= 1;
    }

#pragma unroll
    for (int i = 0; i < 2; i++) {
#pragma unroll
        for (int r = 0; r < 4; r++) {
            const int R = row0 + wrow * 32 + i * 16 + quad * 4 + r;
#pragma unroll
            for (int j = 0; j < 2; j++) {
                const int E = col0 + wcol * 32 + j * 16 + m;
                Out[(size_t)R * D_MODEL + E] = acc[i][j][r] + bo[E];
            }
        }
    }
}

// ---------------------------------------------------------------------------
extern "C" void kernel_launch(void* const* d_in, const int* in_sizes, int n_in,
                              void* d_out, int out_size, void* d_ws, size_t ws_size,
                              hipStream_t stream) {
    const float* x  = (const float*)d_in[0];
    const float* Wq = (const float*)d_in[1];
    const float* Wk = (const float*)d_in[2];
    const float* Wv = (const float*)d_in[3];
    const float* Wo = (const float*)d_in[4];
    const float* bo = (const float*)d_in[5];
    // d_in[6] = causal mask — recomputed from indices, not read.

    const size_t elems  = (size_t)M_TOTAL * D_MODEL;   // 4194304
    const size_t welems = (size_t)D_MODEL * D_MODEL;   // 1048576
    __bf16* xb  = (__bf16*)d_ws;       // seg0: x (bf16) -> later Cc (aliased)
    __bf16* Qb  = xb + elems;
    __bf16* Kb  = Qb + elems;
    __bf16* Vtg = Kb + elems;          // [32][64][2048]  (V^T)
    __bf16* Wqb = Vtg + elems;
    __bf16* Wkb = Wqb + welems;
    __bf16* Wvb = Wkb + welems;
    __bf16* Wob = Wvb + welems;        // end: 40 MB
    __bf16* Cc  = xb;

    // 0) all fp32 -> bf16 conversions in one launch
    convert_all<<<dim3(4096), 256, 0, stream>>>(
        x, Wq, Wk, Wv, Wo, xb, Wqb, Wkb, Wvb, Wob);

    // 1) QKV projections (Q pre-scaled by 0.125*log2e), dbuf prefetch loop
    qkv_kernel<<<dim3(M_TOTAL / 128, 3 * D_MODEL / 128), 256, 0, stream>>>(
        xb, Wqb, Wkb, Wvb, Qb, Kb, Vtg);

    // 2) causal flash attention: balanced strip permutation + setprio
    attn_kernel<<<dim3(BATCH * NUM_HEADS, 32), 256, 0, stream>>>(
        Qb, Kb, Vtg, Cc);

    // 3) output projection + bias -> fp32 out (64x64 tiles, dbuf prefetch)
    oproj_kernel<<<dim3(M_TOTAL / 64, D_MODEL / 64), 256, 0, stream>>>(
        Cc, Wob, bo, (float*)d_out);
}